// Round 5
// baseline (213.407 us; speedup 1.0000x reference)
//
#include <hip/hip_runtime.h>
#include <hip/hip_bf16.h>

constexpr int kHD  = 10;   // hidden dim
constexpr int kP   = 6;    // parts
constexpr int kNE  = 5;    // edges
constexpr int kH   = 128;  // part-map H=W
constexpr int kHin = 64;   // coarse-map H=W

__device__ __forceinline__ float sigm(float v) {
    return 1.0f / (1.0f + __expf(-v));
}

// Single-wave blocks: 64-thread blocks pack up to 16 blocks/CU (VGPR-limited),
// doubling resident waves vs 256-thread blocks at the same VGPR count.
__global__ __launch_bounds__(64)
void Part_Graph_51539607552364_kernel(
    const float* __restrict__ xf,  const float* __restrict__ xh0,
    const float* __restrict__ xh1, const float* __restrict__ xp,
    const float* __restrict__ Wf,  const float* __restrict__ bfb,
    const float* __restrict__ Wh,  const float* __restrict__ bhb,
    const float* __restrict__ Watt, const float* __restrict__ batt,
    const float* __restrict__ Wdp, const float* __restrict__ Wup,
    float* __restrict__ out_xp,
    float* __restrict__ out_att,
    int npix)   // N*128*128
{
    const int idx = blockIdx.x * blockDim.x + threadIdx.x;
    if (idx >= npix) return;
    const int xc = idx & (kH - 1);
    const int yc = (idx >> 7) & (kH - 1);
    const int n  = idx >> 14;

    // ---- bilinear source coords (align_corners=True) ----
    const float scale = (float)(kHin - 1) / (float)(kH - 1);
    float py = (float)yc * scale;
    int   y0 = (int)py; y0 = y0 > (kHin - 2) ? (kHin - 2) : y0;
    float fy = py - (float)y0;
    float px = (float)xc * scale;
    int   x0 = (int)px; x0 = x0 > (kHin - 2) ? (kHin - 2) : x0;
    float fx = px - (float)x0;

    // ================= PHASE 1: issue ALL global loads =================
    float h0r[4 * kHD], h1r[4 * kHD];
    {
        const float* b0 = xh0 + (size_t)(n * kHD) * (kHin * kHin) + y0 * kHin + x0;
        const float* b1 = xh1 + (size_t)(n * kHD) * (kHin * kHin) + y0 * kHin + x0;
        #pragma unroll
        for (int c = 0; c < kHD; ++c) {
            const float* p0 = b0 + c * (kHin * kHin);
            h0r[4 * c + 0] = p0[0];
            h0r[4 * c + 1] = p0[1];
            h0r[4 * c + 2] = p0[kHin];
            h0r[4 * c + 3] = p0[kHin + 1];
            const float* p1 = b1 + c * (kHin * kHin);
            h1r[4 * c + 0] = p1[0];
            h1r[4 * c + 1] = p1[1];
            h1r[4 * c + 2] = p1[kHin];
            h1r[4 * c + 3] = p1[kHin + 1];
        }
    }
    float xfv[kHD];
    {
        const int sy = yc >> 1, sx = xc >> 1;
        const float* b = xf + (size_t)(n * kHD) * (kHin * kHin) + sy * kHin + sx;
        #pragma unroll
        for (int c = 0; c < kHD; ++c) xfv[c] = b[c * (kHin * kHin)];
    }
    float xpv[kP][kHD];
    {
        const float* b = xp + (size_t)(n * kP * kHD) * (kH * kH) + yc * kH + xc;
        #pragma unroll
        for (int p = 0; p < kP; ++p)
            #pragma unroll
            for (int c = 0; c < kHD; ++c)
                xpv[p][c] = b[(size_t)(p * kHD + c) * (kH * kH)];
    }

    // ================= PHASE 2: bilinear reduce ========================
    const float w00 = (1.0f - fy) * (1.0f - fx);
    const float w01 = (1.0f - fy) * fx;
    const float w10 = fy * (1.0f - fx);
    const float w11 = fy * fx;
    float xh0v[kHD], xh1v[kHD];
    #pragma unroll
    for (int c = 0; c < kHD; ++c) {
        xh0v[c] = h0r[4 * c] * w00 + h0r[4 * c + 1] * w01 +
                  h0r[4 * c + 2] * w10 + h0r[4 * c + 3] * w11;
        xh1v[c] = h1r[4 * c] * w00 + h1r[4 * c + 1] * w01 +
                  h1r[4 * c + 2] * w10 + h1r[4 * c + 3] * w11;
    }

    // ================= PHASE 3: attentions =============================
    float attf[kP], atth[kP], dpa[kP];
    #pragma unroll
    for (int p = 0; p < kP; ++p) {
        float af = bfb[p];
        float ah = bhb[p];
        float ad = batt[p];
        #pragma unroll
        for (int c = 0; c < kHD; ++c) {
            const float xhc = (p < 4) ? xh0v[c] : xh1v[c];
            af += xfv[c]    * Wf[p * 2 * kHD + c];
            af += xpv[p][c] * Wf[p * 2 * kHD + kHD + c];
            ah += xhc       * Wh[p * 2 * kHD + c];
            ah += xpv[p][c] * Wh[p * 2 * kHD + kHD + c];
            ad += xpv[p][c] * Watt[p * kHD + c];
        }
        attf[p] = sigm(af);
        atth[p] = sigm(ah);
        dpa[p]  = sigm(ad);
    }

    const size_t pixoff = (size_t)yc * kH + xc;
    #pragma unroll
    for (int p = 0; p < kP; ++p) {
        const float ap = (attf[p] + atth[p] + dpa[p]) * (1.0f / 3.0f);
        out_att[(size_t)(n * kP + p) * (kH * kH) + pixoff] = ap;
    }

    // ================= PHASE 4: edge messages -> xpp ===================
    float xpp[kP][kHD];
    #pragma unroll
    for (int p = 0; p < kP; ++p)
        #pragma unroll
        for (int c = 0; c < kHD; ++c) xpp[p][c] = 0.0f;

    constexpr int EA[kNE] = {0, 1, 2, 1, 4};
    constexpr int EB[kNE] = {1, 2, 3, 4, 5};
    #pragma unroll
    for (int e = 0; e < kNE; ++e) {
        const int a = EA[e], b = EB[e];
        const float sa = 2.0f - dpa[a];   // scales message into b
        const float sb = 2.0f - dpa[b];   // scales message into a
        #pragma unroll
        for (int d = 0; d < kHD; ++d) {
            const float* w = Wdp + (size_t)(e * kHD + d) * (2 * kHD);
            float t = 0.0f;
            #pragma unroll
            for (int c = 0; c < kHD; ++c) t += xpv[a][c] * w[c];
            #pragma unroll
            for (int c = 0; c < kHD; ++c) t += xpv[b][c] * w[kHD + c];
            t = fmaxf(t, 0.0f);
            xpp[b][d] += t * sa;
            xpp[a][d] += t * sb;
        }
    }

    // ================= PHASE 5: update + stores ========================
    #pragma unroll
    for (int p = 0; p < kP; ++p) {
        #pragma unroll
        for (int d = 0; d < kHD; ++d) {
            const float* w = Wup + (size_t)(p * kHD + d) * (4 * kHD);
            float a1 = 0.0f, a2 = 0.0f, a3 = 0.0f, a4 = 0.0f;
            #pragma unroll
            for (int c = 0; c < kHD; ++c) {
                const float xhc = (p < 4) ? xh0v[c] : xh1v[c];
                a1 += xpv[p][c] * w[c];
                a2 += xfv[c]    * w[kHD + c];
                a3 += xhc       * w[2 * kHD + c];
                a4 += xpp[p][c] * w[3 * kHD + c];
            }
            float upd = a1 + attf[p] * a2 + atth[p] * a3 + a4;
            upd = fmaxf(upd, 0.0f);
            float o = xpv[p][d] + upd;
            o = fmaxf(o, 0.0f);
            out_xp[(size_t)(n * kP * kHD + p * kHD + d) * (kH * kH) + pixoff] = o;
        }
    }
}

extern "C" void kernel_launch(void* const* d_in, const int* in_sizes, int n_in,
                              void* d_out, int out_size, void* d_ws, size_t ws_size,
                              hipStream_t stream) {
    const float* xf   = (const float*)d_in[0];
    const float* xh0  = (const float*)d_in[1];
    const float* xh1  = (const float*)d_in[2];
    const float* xp   = (const float*)d_in[3];
    const float* Wf   = (const float*)d_in[4];
    const float* bfb  = (const float*)d_in[5];
    const float* Wh   = (const float*)d_in[6];
    const float* bhb  = (const float*)d_in[7];
    const float* Watt = (const float*)d_in[8];
    const float* batt = (const float*)d_in[9];
    const float* Wdp  = (const float*)d_in[10];
    const float* Wup  = (const float*)d_in[11];

    int N = out_size / ((kP * kHD + kP) * kH * kH);
    if (N <= 0) N = 32;
    const int npix = N * kH * kH;

    float* out_xp  = (float*)d_out;
    float* out_att = out_xp + (size_t)N * kP * kHD * kH * kH;

    const int block = 64;   // 1 wave/block -> finer residency packing
    const int grid = (npix + block - 1) / block;
    Part_Graph_51539607552364_kernel<<<grid, block, 0, stream>>>(
        xf, xh0, xh1, xp, Wf, bfb, Wh, bhb, Watt, batt, Wdp, Wup,
        out_xp, out_att, npix);
}

// Round 6
// 138.559 us; speedup vs baseline: 1.5402x; 1.5402x over previous
//
#include <hip/hip_runtime.h>
#include <hip/hip_bf16.h>

constexpr int kHD  = 10;   // hidden dim
constexpr int kP   = 6;    // parts
constexpr int kNE  = 5;    // edges
constexpr int kH   = 128;  // part-map H=W
constexpr int kHin = 64;   // coarse-map H=W
constexpr int kSeg = 70;   // 60 xh row-segments + 10 xf row-segments (64 floats each)

__device__ __forceinline__ float sigm(float v) {
    return 1.0f / (1.0f + __expf(-v));
}

// Block = 256 threads = 2 output rows of one image.
// Cooperative LDS staging of the bilinear/nearest source rows (the scattered,
// redundantly-fetched loads); xp stays as direct coalesced register loads.
__global__ __launch_bounds__(256, 2)
void Part_Graph_51539607552364_kernel(
    const float* __restrict__ xf,  const float* __restrict__ xh0,
    const float* __restrict__ xh1, const float* __restrict__ xp,
    const float* __restrict__ Wf,  const float* __restrict__ bfb,
    const float* __restrict__ Wh,  const float* __restrict__ bhb,
    const float* __restrict__ Watt, const float* __restrict__ batt,
    const float* __restrict__ Wdp, const float* __restrict__ Wup,
    float* __restrict__ out_xp,
    float* __restrict__ out_att)
{
    __shared__ float lds[kSeg * kHin];   // 70*64*4 = 17.9 KB

    const int bid = blockIdx.x;
    const int n   = bid >> 6;           // 64 blocks per image
    const int R   = bid & 63;           // row-pair index; rows yA=2R, yA+1
    const int yA  = R * 2;

    const float scale = (float)(kHin - 1) / (float)(kH - 1);
    int ry0 = (int)((float)yA * scale);
    ry0 = ry0 > (kHin - 2) ? (kHin - 2) : ry0;   // block's base source row

    // ---- cooperative staging: 70 segments of 64 floats ----
    {
        const int w = threadIdx.x >> 6;       // wave id 0..3
        const int l = threadIdx.x & 63;       // lane
        for (int s = w; s < kSeg; s += 4) {   // s is wave-uniform
            const float* src;
            if (s < 60) {
                const int map = s / 30, rem = s % 30;
                const int ch = rem / 3, r3 = rem % 3;
                int srow = ry0 + r3;
                srow = srow > (kHin - 1) ? (kHin - 1) : srow;
                src = (map ? xh1 : xh0) +
                      ((size_t)(n * kHD + ch) * kHin + srow) * kHin;
            } else {
                const int ch = s - 60;
                src = xf + ((size_t)(n * kHD + ch) * kHin + R) * kHin;
            }
            lds[s * kHin + l] = src[l];
        }
    }
    __syncthreads();

    // ---- per-thread pixel ----
    const int ly = threadIdx.x >> 7;          // 0/1 within the row pair
    const int xc = threadIdx.x & (kH - 1);
    const int yc = yA + ly;

    // bilinear coords
    float py = (float)yc * scale;
    int   y0 = (int)py; y0 = y0 > (kHin - 2) ? (kHin - 2) : y0;
    const float fy = py - (float)y0;
    const int   d0 = y0 - ry0;                // 0 or 1 (wave-uniform)
    float px = (float)xc * scale;
    int   x0 = (int)px; x0 = x0 > (kHin - 2) ? (kHin - 2) : x0;
    const float fx = px - (float)x0;

    const float w00 = (1.0f - fy) * (1.0f - fx);
    const float w01 = (1.0f - fy) * fx;
    const float w10 = fy * (1.0f - fx);
    const float w11 = fy * fx;

    // xh windows from LDS; lds segment for (map,ch,row d) = (map*30+ch*3+d)
    float xh0v[kHD], xh1v[kHD];
    #pragma unroll
    for (int c = 0; c < kHD; ++c) {
        {
            const float* r0 = &lds[(0 * 30 + c * 3 + d0) * kHin];
            xh0v[c] = r0[x0] * w00 + r0[x0 + 1] * w01 +
                      r0[kHin + x0] * w10 + r0[kHin + x0 + 1] * w11;
        }
        {
            const float* r1 = &lds[(1 * 30 + c * 3 + d0) * kHin];
            xh1v[c] = r1[x0] * w00 + r1[x0 + 1] * w01 +
                      r1[kHin + x0] * w10 + r1[kHin + x0 + 1] * w11;
        }
    }
    // xf nearest from LDS
    const int sx = xc >> 1;
    float xfv[kHD];
    #pragma unroll
    for (int c = 0; c < kHD; ++c) xfv[c] = lds[(60 + c) * kHin + sx];

    // ---- xp: direct coalesced loads ----
    float xpv[kP][kHD];
    {
        const float* b = xp + (size_t)(n * kP * kHD) * (kH * kH) + yc * kH + xc;
        #pragma unroll
        for (int p = 0; p < kP; ++p)
            #pragma unroll
            for (int c = 0; c < kHD; ++c)
                xpv[p][c] = b[(size_t)(p * kHD + c) * (kH * kH)];
    }

    // ---- attentions ----
    float attf[kP], atth[kP], dpa[kP];
    #pragma unroll
    for (int p = 0; p < kP; ++p) {
        float af = bfb[p];
        float ah = bhb[p];
        float ad = batt[p];
        #pragma unroll
        for (int c = 0; c < kHD; ++c) {
            const float xhc = (p < 4) ? xh0v[c] : xh1v[c];
            af += xfv[c]    * Wf[p * 2 * kHD + c];
            af += xpv[p][c] * Wf[p * 2 * kHD + kHD + c];
            ah += xhc       * Wh[p * 2 * kHD + c];
            ah += xpv[p][c] * Wh[p * 2 * kHD + kHD + c];
            ad += xpv[p][c] * Watt[p * kHD + c];
        }
        attf[p] = sigm(af);
        atth[p] = sigm(ah);
        dpa[p]  = sigm(ad);
    }

    const size_t pixoff = (size_t)yc * kH + xc;
    #pragma unroll
    for (int p = 0; p < kP; ++p) {
        const float ap = (attf[p] + atth[p] + dpa[p]) * (1.0f / 3.0f);
        out_att[(size_t)(n * kP + p) * (kH * kH) + pixoff] = ap;
    }

    // ---- edge messages -> xpp ----
    float xpp[kP][kHD];
    #pragma unroll
    for (int p = 0; p < kP; ++p)
        #pragma unroll
        for (int c = 0; c < kHD; ++c) xpp[p][c] = 0.0f;

    constexpr int EA[kNE] = {0, 1, 2, 1, 4};
    constexpr int EB[kNE] = {1, 2, 3, 4, 5};
    #pragma unroll
    for (int e = 0; e < kNE; ++e) {
        const int a = EA[e], b = EB[e];
        const float sa = 2.0f - dpa[a];
        const float sb = 2.0f - dpa[b];
        #pragma unroll
        for (int d = 0; d < kHD; ++d) {
            const float* w = Wdp + (size_t)(e * kHD + d) * (2 * kHD);
            float t = 0.0f;
            #pragma unroll
            for (int c = 0; c < kHD; ++c) t += xpv[a][c] * w[c];
            #pragma unroll
            for (int c = 0; c < kHD; ++c) t += xpv[b][c] * w[kHD + c];
            t = fmaxf(t, 0.0f);
            xpp[b][d] += t * sa;
            xpp[a][d] += t * sb;
        }
    }

    // ---- update + stores ----
    #pragma unroll
    for (int p = 0; p < kP; ++p) {
        #pragma unroll
        for (int d = 0; d < kHD; ++d) {
            const float* w = Wup + (size_t)(p * kHD + d) * (4 * kHD);
            float a1 = 0.0f, a2 = 0.0f, a3 = 0.0f, a4 = 0.0f;
            #pragma unroll
            for (int c = 0; c < kHD; ++c) {
                const float xhc = (p < 4) ? xh0v[c] : xh1v[c];
                a1 += xpv[p][c] * w[c];
                a2 += xfv[c]    * w[kHD + c];
                a3 += xhc       * w[2 * kHD + c];
                a4 += xpp[p][c] * w[3 * kHD + c];
            }
            float upd = a1 + attf[p] * a2 + atth[p] * a3 + a4;
            upd = fmaxf(upd, 0.0f);
            float o = xpv[p][d] + upd;
            o = fmaxf(o, 0.0f);
            out_xp[(size_t)(n * kP * kHD + p * kHD + d) * (kH * kH) + pixoff] = o;
        }
    }
}

extern "C" void kernel_launch(void* const* d_in, const int* in_sizes, int n_in,
                              void* d_out, int out_size, void* d_ws, size_t ws_size,
                              hipStream_t stream) {
    const float* xf   = (const float*)d_in[0];
    const float* xh0  = (const float*)d_in[1];
    const float* xh1  = (const float*)d_in[2];
    const float* xp   = (const float*)d_in[3];
    const float* Wf   = (const float*)d_in[4];
    const float* bfb  = (const float*)d_in[5];
    const float* Wh   = (const float*)d_in[6];
    const float* bhb  = (const float*)d_in[7];
    const float* Watt = (const float*)d_in[8];
    const float* batt = (const float*)d_in[9];
    const float* Wdp  = (const float*)d_in[10];
    const float* Wup  = (const float*)d_in[11];

    int N = out_size / ((kP * kHD + kP) * kH * kH);
    if (N <= 0) N = 32;
    const int npix = N * kH * kH;

    float* out_xp  = (float*)d_out;
    float* out_att = out_xp + (size_t)N * kP * kHD * kH * kH;

    const int block = 256;                 // 2 rows per block
    const int grid = npix / block;         // 64 blocks per image
    Part_Graph_51539607552364_kernel<<<grid, block, 0, stream>>>(
        xf, xh0, xh1, xp, Wf, bfb, Wh, bhb, Watt, batt, Wdp, Wup,
        out_xp, out_att);
}